// Round 10
// baseline (271.303 us; speedup 1.0000x reference)
//
#include <hip/hip_runtime.h>
#include <hip/hip_bf16.h>
#include <hip/hip_fp16.h>
#include <cstdint>

// ---------- types ----------
typedef unsigned short us;
typedef us   us4 __attribute__((ext_vector_type(4)));
typedef short s8v __attribute__((ext_vector_type(8)));   // 8 bf16 (4 VGPRs) MFMA A/B frag
typedef float f4v __attribute__((ext_vector_type(4)));   // MFMA C/D frag
typedef __fp16 pk2 __attribute__((ext_vector_type(2))); // cvt_pkrtz result type

// Problem constants (B=4, S=4096, D=1024 fixed by setup_inputs)
#define BB 4
#define SS 4096
#define DD 1024
#define MM (BB * SS)      // 16384
#define NN (2 * DD)       // 2048
#define KK DD             // 1024

// GEMM tiling — R10: 128x256 block (128 channels), 4 waves, wave-tile 64x128.
// Why: per-K-tile per-CU at the old 64x64 wave-tile, LDS reads = 768 cyc
// (16 ds_read_b128/wave x 12cyc x 4 waves) vs matrix 620 cyc -> LDS-bound.
// 64x128 wave-tile: 12 reads feed 32 MFMA -> LDS 576 < matrix 620 cyc.
#define BM 128
#define BN 256            // W rows = 128 channels
#define BK 64

// Scan chunking
#define CHUNK 32
#define NC (SS / CHUNK)   // 128
#define BDD (BB * DD)     // 4096 sequences
#define DP (DD / 2)       // 512 channel-pairs (pass3)

// ---------- fp32 -> bf16 (RNE) ----------
__device__ inline us f2bf(float f) {
  unsigned u = __float_as_uint(f);
  u += 0x7fffu + ((u >> 16) & 1u);
  return (us)(u >> 16);
}

// one launch converts both x and W (x occupies the first nx/4 quads).
__global__ __launch_bounds__(256) void cvt_both(const float* __restrict__ x,
                                                const float* __restrict__ W,
                                                us* __restrict__ xb,
                                                us* __restrict__ wb,
                                                long nx) {
  long i = ((long)blockIdx.x * 256 + threadIdx.x) * 4;
  const float* in;
  us* out;
  if (i < nx) { in = x + i; out = xb + i; }
  else        { in = W + (i - nx); out = wb + (i - nx); }
  float4 a = *(const float4*)in;
  us4 o;
  o[0] = f2bf(a.x); o[1] = f2bf(a.y); o[2] = f2bf(a.z); o[3] = f2bf(a.w);
  *(us4*)out = o;
}

// ---------- async global->LDS, 16B per lane ----------
#define GLD16(g, l)                                                        \
  __builtin_amdgcn_global_load_lds(                                        \
      (const __attribute__((address_space(1))) void*)(g),                  \
      (__attribute__((address_space(3))) void*)(l), 16, 0, 0)

// ---------- gate math ----------
// h_t = coef*h_{t-1} + v ;  coef = sigmoid(-gate), v = sigmoid(gate)*g(hidden)
__device__ inline void gate_cv(float hid, float gat, float& coef, float& v) {
  float e = __expf(gat);
  coef = __builtin_amdgcn_rcpf(1.0f + e);      // sigmoid(-gate)
  float z = 1.0f - coef;                        // sigmoid(gate), robust at e=inf
  float eh = __expf(hid < 0.0f ? hid : 0.0f);   // only meaningful on neg path
  float gneg = eh * __builtin_amdgcn_rcpf(1.0f + eh);  // eh<=1: safe
  float g = (hid >= 0.0f) ? (hid + 0.5f) : gneg;
  v = z * g;
}

// ---------- fused GEMM + gate epilogue + chunk-local scan (pass1) ----------
// Block: rows [bm,bm+128) x channels [d0,d0+128) (256 W rows). 4 waves in
// 2(M)x2(N) grid; wave-tile 64 rows x 128 B-rows: af[4] x bf[8] -> 32 MFMA
// per kk (12 ds_read_b128 per kk -> matrix-bound, see above).
// Same kt/kk K-order per output as R8 -> bit-identical acc.
// Epilogue T: [128 rows][128 ch] uint = 64 KB (LDS block 64 KB, 2 blocks/CU).
__global__ __launch_bounds__(256) void gemm_fused(const us* __restrict__ A,
                                                  const us* __restrict__ B,
                                                  unsigned* __restrict__ cv,
                                                  float* __restrict__ cp,
                                                  float* __restrict__ ch) {
  __shared__ __align__(16) us smem[32768];   // 64 KB (staging 48 KB, T 64 KB)
  us* As = smem;                              // [128][64]
  us* Bs = smem + BM * BK;                    // [256][64]
  unsigned* T = (unsigned*)smem;              // epilogue: [128][128]

  const int tid  = threadIdx.x;
  const int lane = tid & 63;
  const int w    = tid >> 6;      // wave 0..3
  const int wm   = w & 1;         // M-half (64 rows)
  const int wn   = w >> 1;        // N-half (128 B-rows)
  const long bm  = (long)blockIdx.x * BM;
  const int  d0  = blockIdx.y * 128;

  // staging: each global_load_lds covers 8 rows x 64 cols (1 KiB)
  const int srow = lane >> 3;                 // row within 8-row group
  const int sseg = (lane & 7) ^ srow;         // XOR-permuted source segment

  const int fr = lane & 15;
  const int fq = lane >> 4;                   // 0..3

  int aoff[4][2], boff[8][2];
#pragma unroll
  for (int mt = 0; mt < 4; ++mt) {
    int row = wm * 64 + mt * 16 + fr;
#pragma unroll
    for (int kk = 0; kk < 2; ++kk) {
      int seg = kk * 4 + fq;
      aoff[mt][kk] = row * BK + ((seg ^ (row & 7)) * 8);
    }
  }
#pragma unroll
  for (int nt = 0; nt < 8; ++nt) {
    int row = wn * 128 + nt * 16 + fr;
#pragma unroll
    for (int kk = 0; kk < 2; ++kk) {
      int seg = kk * 4 + fq;
      boff[nt][kk] = row * BK + ((seg ^ (row & 7)) * 8);
    }
  }

  f4v acc[4][8] = {};

  // staging pointers: A 4 ops/wave (32 rows), B 8 ops/wave (64 rows)
  const us* Ap[4];
  const us* Bp[8];
#pragma unroll
  for (int i = 0; i < 4; ++i) {
    int lr = w * 32 + i * 8 + srow;           // A local row
    Ap[i] = A + (bm + lr) * (long)KK + sseg * 8;
  }
#pragma unroll
  for (int j = 0; j < 8; ++j) {
    int lr = w * 64 + j * 8 + srow;           // B local row 0..255
    // 32-row groups = 16 hid + 16 gate rows for 16 channels
    int wrow = d0 + ((lr >> 5) << 4) + (lr & 15) + (((lr >> 4) & 1) << 10);
    Bp[j] = B + (long)wrow * KK + sseg * 8;
  }

  for (int kt = 0; kt < KK / BK; ++kt) {
    __syncthreads();   // previous tile's reads done before overwrite
#pragma unroll
    for (int i = 0; i < 4; ++i) {
      GLD16(Ap[i], &As[(w * 32 + i * 8) * BK]);
      Ap[i] += BK;
    }
#pragma unroll
    for (int j = 0; j < 8; ++j) {
      GLD16(Bp[j], &Bs[(w * 64 + j * 8) * BK]);
      Bp[j] += BK;
    }
    __syncthreads();   // staging visible

#pragma unroll
    for (int kk = 0; kk < 2; ++kk) {
      s8v af[4], bf[8];
#pragma unroll
      for (int mt = 0; mt < 4; ++mt) af[mt] = *(const s8v*)&As[aoff[mt][kk]];
#pragma unroll
      for (int nt = 0; nt < 8; ++nt) bf[nt] = *(const s8v*)&Bs[boff[nt][kk]];
#pragma unroll
      for (int mt = 0; mt < 4; ++mt)
#pragma unroll
        for (int nt = 0; nt < 8; ++nt)
          acc[mt][nt] = __builtin_amdgcn_mfma_f32_16x16x32_bf16(
              af[mt], bf[nt], acc[mt][nt], 0, 0, 0);
    }
  }

  // ---- epilogue ----
  __syncthreads();   // all waves done with As/Bs; reuse LDS as T
  // C/D row = fq*4 + r, col = fr (m89 layout); hid/gate pair = (nt=2p, 2p+1)
#pragma unroll
  for (int mt = 0; mt < 4; ++mt) {
    int lr0 = wm * 64 + mt * 16 + fq * 4;     // local row base
#pragma unroll
    for (int p = 0; p < 4; ++p) {
      int ld = (wn * 4 + p) * 16 + fr;        // local channel 0..127
      f4v hv = acc[mt][2 * p];
      f4v gv = acc[mt][2 * p + 1];
#pragma unroll
      for (int r = 0; r < 4; ++r) {
        float coef, v;
        gate_cv(hv[r], gv[r], coef, v);
        pk2 pk = __builtin_amdgcn_cvt_pkrtz(coef, v);   // (lo=coef, hi=v)
        T[(lr0 + r) * 128 + ld] = __builtin_bit_cast(unsigned, pk);
      }
    }
  }
  __syncthreads();   // transpose complete

  // (1) coalesced cv writes: 4096 uint4 chunks (128 rows x 32), 16 per thread
#pragma unroll
  for (int j = 0; j < 16; ++j) {
    int chunk = j * 256 + tid;
    int row = chunk >> 5;                     // 0..127
    int q   = chunk & 31;                     // 16B chunk within row
    uint4 val = *(const uint4*)&T[row * 128 + q * 4];
    *(uint4*)(cv + (size_t)(bm + row) * DD + d0 + q * 4) = val;
  }

  // (2) chunk-local scan: 4 chunks x 128 ch = 512 tasks, 2 per thread
  {
    const int d  = tid & 127;
    const int c0 = tid >> 7;                  // 0..1
    const int b  = (int)(bm / SS);
    const int cg0 = (int)((bm % SS) / CHUNK);
#pragma unroll
    for (int half = 0; half < 2; ++half) {
      const int c = c0 + 2 * half;            // local chunk 0..3
      float P = 1.0f, h = 0.0f;
#pragma unroll
      for (int i = 0; i < CHUNK; ++i) {
        unsigned u = T[(c * CHUNK + i) * 128 + d];
        __half2 hv = *(__half2*)&u;
        float cf = __half2float(hv.x);
        h = fmaf(cf, h, __half2float(hv.y));
        P *= cf;
      }
      const int idx = (cg0 + c) * BDD + b * DD + d0 + d;   // [chunk][b][d]
      cp[idx] = P;
      ch[idx] = h;
    }
  }
}

// pass2: serial scan over NC chunk summaries per sequence; 4096 threads.
__global__ __launch_bounds__(256) void scan_pass2(const float* __restrict__ cp,
                                                  const float* __restrict__ ch,
                                                  float* __restrict__ carry) {
  const int bd = blockIdx.x * 256 + threadIdx.x;  // 0..4095
  float h = 0.0f;
  for (int cb = 0; cb < NC; cb += 16) {
    float p[16], v[16];
#pragma unroll
    for (int i = 0; i < 16; ++i) {
      p[i] = cp[(cb + i) * BDD + bd];
      v[i] = ch[(cb + i) * BDD + bd];
    }
#pragma unroll
    for (int i = 0; i < 16; ++i) {
      carry[(cb + i) * BDD + bd] = h;               // carry INTO chunk cb+i
      h = fmaf(p[i], h, v[i]);
    }
  }
}

// pass3: IN-PLACE — cv aliases d_out; reads half2 (coef,v), overwrites with
// fp32 h. NO __restrict__ on cv/out (alias). All 32 loads precede stores in
// program order; thread regions disjoint. fma order identical -> bit-identical.
__global__ __launch_bounds__(256) void scan_pass3(const uint2* cv,
                                                  const float* __restrict__ carry,
                                                  float2* out) {
  const int dp = blockIdx.x * 256 + threadIdx.x;  // 0..511 channel-pair
  const int c = blockIdx.y;
  const int b = blockIdx.z;
  const size_t rbase = ((size_t)b * SS + (size_t)c * CHUNK) * DP + dp;
  const uint2* base = cv + rbase;
  float2* obase = out + rbase;
  float2 h = *(const float2*)&carry[c * BDD + b * DD + 2 * dp];

  uint2 u[CHUNK];
#pragma unroll
  for (int t = 0; t < CHUNK; ++t) u[t] = base[(size_t)t * DP];   // all loads first
#pragma unroll
  for (int t = 0; t < CHUNK; ++t) {
    __half2 a  = *(__half2*)&u[t].x;
    __half2 bq = *(__half2*)&u[t].y;
    h.x = fmaf(__half2float(a.x),  h.x, __half2float(a.y));
    h.y = fmaf(__half2float(bq.x), h.y, __half2float(bq.y));
    obase[(size_t)t * DP] = h;
  }
}

// ---------- launch ----------
extern "C" void kernel_launch(void* const* d_in, const int* in_sizes, int n_in,
                              void* d_out, int out_size, void* d_ws, size_t ws_size,
                              hipStream_t stream) {
  const float* x = (const float*)d_in[0];   // [4,4096,1024] fp32
  const float* W = (const float*)d_in[1];   // [2048,1024]  fp32

  const long nx = (long)MM * KK;            // 16,777,216
  const long nw = (long)NN * KK;            //  2,097,152

  // cv lives in d_out (pass3 consumes it in place). Workspace 42 MiB.
  unsigned* cv = (unsigned*)d_out;

  char* ws = (char*)d_ws;
  us* xb = (us*)ws;                  ws += (size_t)nx * sizeof(us);            // 32 MiB
  us* wb = (us*)ws;                  ws += (size_t)nw * sizeof(us);            //  4 MiB
  float* cp = (float*)ws;            ws += (size_t)NC * BDD * sizeof(float);   //  2 MiB
  float* chh = (float*)ws;           ws += (size_t)NC * BDD * sizeof(float);   //  2 MiB
  float* carry = (float*)ws;         ws += (size_t)NC * BDD * sizeof(float);   //  2 MiB

  cvt_both<<<(int)((nx + nw) / 4 / 256), 256, 0, stream>>>(x, W, xb, wb, nx);

  gemm_fused<<<dim3(MM / BM, DD / 128), 256, 0, stream>>>(xb, wb, cv, cp, chh);

  scan_pass2<<<dim3(BDD / 256), 256, 0, stream>>>(cp, chh, carry);
  scan_pass3<<<dim3(DP / 256, NC, BB), 256, 0, stream>>>((const uint2*)cv, carry,
                                                         (float2*)d_out);
}

// Round 11
// 225.146 us; speedup vs baseline: 1.2050x; 1.2050x over previous
//
#include <hip/hip_runtime.h>
#include <hip/hip_bf16.h>
#include <hip/hip_fp16.h>
#include <cstdint>

// ---------- types ----------
typedef unsigned short us;
typedef us   us4 __attribute__((ext_vector_type(4)));
typedef short s8v __attribute__((ext_vector_type(8)));   // 8 bf16 (4 VGPRs) MFMA A/B frag
typedef float f4v __attribute__((ext_vector_type(4)));   // MFMA C/D frag
typedef __fp16 pk2 __attribute__((ext_vector_type(2))); // cvt_pkrtz result type

// Problem constants (B=4, S=4096, D=1024 fixed by setup_inputs)
#define BB 4
#define SS 4096
#define DD 1024
#define MM (BB * SS)      // 16384
#define NN (2 * DD)       // 2048
#define KK DD             // 1024

// GEMM tiling — R11: exact revert to the measured-best R8 configuration.
// Evidence series (blocks/CU dominates): 32KB/128^2 = 91us (R8);
// 64KB/128x256 = 141us (R10); 128KB/256^2 8-phase = 100us (R4).
// The 2-phase barrier drain is hidden by cross-block overlap, so LDS/VGPR
// frugality beats per-K-loop micro-optimizations for this fused epilogue.
#define BM 128
#define BN 128
#define BK 64

// Scan chunking
#define CHUNK 32
#define NC (SS / CHUNK)   // 128
#define BDD (BB * DD)     // 4096 sequences
#define DP (DD / 2)       // 512 channel-pairs (pass3)

// ---------- fp32 -> bf16 (RNE) ----------
__device__ inline us f2bf(float f) {
  unsigned u = __float_as_uint(f);
  u += 0x7fffu + ((u >> 16) & 1u);
  return (us)(u >> 16);
}

// one launch converts both x and W (x occupies the first nx/4 quads).
__global__ __launch_bounds__(256) void cvt_both(const float* __restrict__ x,
                                                const float* __restrict__ W,
                                                us* __restrict__ xb,
                                                us* __restrict__ wb,
                                                long nx) {
  long i = ((long)blockIdx.x * 256 + threadIdx.x) * 4;
  const float* in;
  us* out;
  if (i < nx) { in = x + i; out = xb + i; }
  else        { in = W + (i - nx); out = wb + (i - nx); }
  float4 a = *(const float4*)in;
  us4 o;
  o[0] = f2bf(a.x); o[1] = f2bf(a.y); o[2] = f2bf(a.z); o[3] = f2bf(a.w);
  *(us4*)out = o;
}

// ---------- async global->LDS, 16B per lane ----------
#define GLD16(g, l)                                                        \
  __builtin_amdgcn_global_load_lds(                                        \
      (const __attribute__((address_space(1))) void*)(g),                  \
      (__attribute__((address_space(3))) void*)(l), 16, 0, 0)

// ---------- gate math ----------
// h_t = coef*h_{t-1} + v ;  coef = sigmoid(-gate), v = sigmoid(gate)*g(hidden)
// g(x) = x+0.5 (x>=0) else sigmoid(x). Fast: v_exp + v_rcp (1 ulp), no divides.
__device__ inline void gate_cv(float hid, float gat, float& coef, float& v) {
  float e = __expf(gat);
  coef = __builtin_amdgcn_rcpf(1.0f + e);      // sigmoid(-gate)
  float z = 1.0f - coef;                        // sigmoid(gate), robust at e=inf
  float eh = __expf(hid < 0.0f ? hid : 0.0f);   // only meaningful on neg path
  float gneg = eh * __builtin_amdgcn_rcpf(1.0f + eh);  // eh<=1: safe
  float g = (hid >= 0.0f) ? (hid + 0.5f) : gneg;
  v = z * g;
}

// ---------- fused GEMM + gate epilogue + chunk-local scan (pass1) ----------
// (R1/R8 structure, measured 91us / 755 TF.) Block covers 128 consecutive
// rows (= 4 chunks of 32 t's within one batch b) x 64 output channels
// [d0,d0+64). W-row permutation pairs hid/gate per lane. cv aliases d_out.
__global__ __launch_bounds__(256) void gemm_fused(const us* __restrict__ A,
                                                  const us* __restrict__ B,
                                                  unsigned* __restrict__ cv,
                                                  float* __restrict__ cp,
                                                  float* __restrict__ ch) {
  __shared__ __align__(16) us smem[BM * BK + BN * BK];  // 32 KB
  us* As = smem;
  us* Bs = smem + BM * BK;
  unsigned* T = (unsigned*)smem;    // epilogue reuse: [128 rows][64 d] uint

  const int tid  = threadIdx.x;
  const int lane = tid & 63;
  const int w    = tid >> 6;      // wave 0..3
  const int wm   = w & 1;         // 2x2 wave grid
  const int wn   = w >> 1;
  const long bm  = (long)blockIdx.x * BM;
  const int  d0  = blockIdx.y * 64;

  // staging: each global_load_lds covers 8 rows x 64 cols (1 KiB)
  const int srow = lane >> 3;                 // row within 8-row group
  const int sseg = (lane & 7) ^ srow;         // XOR-permuted source segment

  const int fr = lane & 15;
  const int fq = lane >> 4;                   // 0..3

  int aoff[4][2], boff[4][2];
#pragma unroll
  for (int mt = 0; mt < 4; ++mt) {
    int row = wm * 64 + mt * 16 + fr;
#pragma unroll
    for (int kk = 0; kk < 2; ++kk) {
      int seg = kk * 4 + fq;
      aoff[mt][kk] = row * BK + ((seg ^ (row & 7)) * 8);
    }
  }
#pragma unroll
  for (int nt = 0; nt < 4; ++nt) {
    int row = wn * 64 + nt * 16 + fr;
#pragma unroll
    for (int kk = 0; kk < 2; ++kk) {
      int seg = kk * 4 + fq;
      boff[nt][kk] = row * BK + ((seg ^ (row & 7)) * 8);
    }
  }

  f4v acc[4][4] = {};

  const us* Ap[4];
  const us* Bp[4];
#pragma unroll
  for (int i = 0; i < 4; ++i) {
    int lr = w * 32 + i * 8 + srow;           // local tile row
    Ap[i] = A + (bm + lr) * (long)KK + sseg * 8;
    int wrow = d0 + ((lr >> 5) << 4) + (lr & 15) + (((lr >> 4) & 1) << 10);
    Bp[i] = B + (long)wrow * KK + sseg * 8;
  }

  for (int kt = 0; kt < KK / BK; ++kt) {
    __syncthreads();   // previous tile's reads done before overwrite
#pragma unroll
    for (int i = 0; i < 4; ++i) {
      GLD16(Ap[i], &As[(w * 32 + i * 8) * BK]);
      GLD16(Bp[i], &Bs[(w * 32 + i * 8) * BK]);
      Ap[i] += BK;
      Bp[i] += BK;
    }
    __syncthreads();   // staging visible

#pragma unroll
    for (int kk = 0; kk < 2; ++kk) {
      s8v af[4], bf[4];
#pragma unroll
      for (int mt = 0; mt < 4; ++mt) af[mt] = *(const s8v*)&As[aoff[mt][kk]];
#pragma unroll
      for (int nt = 0; nt < 4; ++nt) bf[nt] = *(const s8v*)&Bs[boff[nt][kk]];
#pragma unroll
      for (int mt = 0; mt < 4; ++mt)
#pragma unroll
        for (int nt = 0; nt < 4; ++nt)
          acc[mt][nt] = __builtin_amdgcn_mfma_f32_16x16x32_bf16(
              af[mt], bf[nt], acc[mt][nt], 0, 0, 0);
    }
  }

  // ---- epilogue ----
  __syncthreads();   // all waves done with As/Bs; reuse LDS as T
  // C/D row = fq*4 + r, col = fr (m89 layout); hid/gate pair = (nt=2p, 2p+1)
#pragma unroll
  for (int mt = 0; mt < 4; ++mt) {
    int lr0 = wm * 64 + mt * 16 + fq * 4;     // local row base
#pragma unroll
    for (int p = 0; p < 2; ++p) {
      int ld = (wn * 2 + p) * 16 + fr;        // local d
      f4v hv = acc[mt][2 * p];
      f4v gv = acc[mt][2 * p + 1];
#pragma unroll
      for (int r = 0; r < 4; ++r) {
        float coef, v;
        gate_cv(hv[r], gv[r], coef, v);
        pk2 pk = __builtin_amdgcn_cvt_pkrtz(coef, v);   // (lo=coef, hi=v)
        T[(lr0 + r) * 64 + ld] = __builtin_bit_cast(unsigned, pk);
      }
    }
  }
  __syncthreads();   // transpose complete

  // (1) coalesced cv writes: 2048 uint4 chunks (128 rows x 16), 8 per thread
#pragma unroll
  for (int j = 0; j < 8; ++j) {
    int chunk = j * 256 + tid;
    int row = chunk >> 4;                     // 0..127
    int q   = chunk & 15;                     // 16B chunk within row
    uint4 val = *(const uint4*)&T[row * 64 + q * 4];
    *(uint4*)(cv + (size_t)(bm + row) * DD + d0 + q * 4) = val;
  }

  // (2) chunk-local scan: thread -> (local chunk c = tid>>6, d = tid&63)
  {
    const int d = tid & 63;
    const int c = tid >> 6;                   // 0..3
    float P = 1.0f, h = 0.0f;
#pragma unroll
    for (int i = 0; i < CHUNK; ++i) {
      unsigned u = T[(c * CHUNK + i) * 64 + d];
      __half2 hv = *(__half2*)&u;
      float cf = __half2float(hv.x);
      h = fmaf(cf, h, __half2float(hv.y));
      P *= cf;
    }
    const int b  = (int)(bm / SS);
    const int cg = (int)((bm % SS) / CHUNK) + c;   // global chunk 0..127
    const int idx = cg * BDD + b * DD + d0 + d;    // [chunk][b][d]
    cp[idx] = P;
    ch[idx] = h;
  }
}

// pass2: serial scan over NC chunk summaries per sequence; 4096 threads.
__global__ __launch_bounds__(256) void scan_pass2(const float* __restrict__ cp,
                                                  const float* __restrict__ ch,
                                                  float* __restrict__ carry) {
  const int bd = blockIdx.x * 256 + threadIdx.x;  // 0..4095
  float h = 0.0f;
  for (int cb = 0; cb < NC; cb += 16) {
    float p[16], v[16];
#pragma unroll
    for (int i = 0; i < 16; ++i) {
      p[i] = cp[(cb + i) * BDD + bd];
      v[i] = ch[(cb + i) * BDD + bd];
    }
#pragma unroll
    for (int i = 0; i < 16; ++i) {
      carry[(cb + i) * BDD + bd] = h;               // carry INTO chunk cb+i
      h = fmaf(p[i], h, v[i]);
    }
  }
}

// pass3: IN-PLACE — cv aliases d_out; reads half2 (coef,v), overwrites with
// fp32 h. NO __restrict__ on cv/out (alias). All 32 loads precede stores in
// program order; thread regions disjoint. fma order identical -> bit-identical.
__global__ __launch_bounds__(256) void scan_pass3(const uint2* cv,
                                                  const float* __restrict__ carry,
                                                  float2* out) {
  const int dp = blockIdx.x * 256 + threadIdx.x;  // 0..511 channel-pair
  const int c = blockIdx.y;
  const int b = blockIdx.z;
  const size_t rbase = ((size_t)b * SS + (size_t)c * CHUNK) * DP + dp;
  const uint2* base = cv + rbase;
  float2* obase = out + rbase;
  float2 h = *(const float2*)&carry[c * BDD + b * DD + 2 * dp];

  uint2 u[CHUNK];
#pragma unroll
  for (int t = 0; t < CHUNK; ++t) u[t] = base[(size_t)t * DP];   // all loads first
#pragma unroll
  for (int t = 0; t < CHUNK; ++t) {
    __half2 a  = *(__half2*)&u[t].x;
    __half2 bq = *(__half2*)&u[t].y;
    h.x = fmaf(__half2float(a.x),  h.x, __half2float(a.y));
    h.y = fmaf(__half2float(bq.x), h.y, __half2float(bq.y));
    obase[(size_t)t * DP] = h;
  }
}

// ---------- launch ----------
extern "C" void kernel_launch(void* const* d_in, const int* in_sizes, int n_in,
                              void* d_out, int out_size, void* d_ws, size_t ws_size,
                              hipStream_t stream) {
  const float* x = (const float*)d_in[0];   // [4,4096,1024] fp32
  const float* W = (const float*)d_in[1];   // [2048,1024]  fp32

  const long nx = (long)MM * KK;            // 16,777,216
  const long nw = (long)NN * KK;            //  2,097,152

  // cv lives in d_out (pass3 consumes it in place). Workspace 42 MiB.
  unsigned* cv = (unsigned*)d_out;

  char* ws = (char*)d_ws;
  us* xb = (us*)ws;                  ws += (size_t)nx * sizeof(us);            // 32 MiB
  us* wb = (us*)ws;                  ws += (size_t)nw * sizeof(us);            //  4 MiB
  float* cp = (float*)ws;            ws += (size_t)NC * BDD * sizeof(float);   //  2 MiB
  float* chh = (float*)ws;           ws += (size_t)NC * BDD * sizeof(float);   //  2 MiB
  float* carry = (float*)ws;         ws += (size_t)NC * BDD * sizeof(float);   //  2 MiB

  cvt_both<<<(int)((nx + nw) / 4 / 256), 256, 0, stream>>>(x, W, xb, wb, nx);

  gemm_fused<<<dim3(MM / BM, DD / 64), 256, 0, stream>>>(xb, wb, cv, cp, chh);

  scan_pass2<<<dim3(BDD / 256), 256, 0, stream>>>(cp, chh, carry);
  scan_pass3<<<dim3(DP / 256, NC, BB), 256, 0, stream>>>((const uint2*)cv, carry,
                                                         (float2*)d_out);
}